// Round 9
// baseline (70.354 us; speedup 1.0000x reference)
//
#include <hip/hip_runtime.h>
#include <hip/hip_fp16.h>

// INT4 asymmetric weight decompressor.
// d_in[0] x:        33,554,432 int32, each holding 2 uint4 nibbles (low first)
// d_in[1] scale:    524,288 float32 (fp16 values upcast by the harness)
// d_in[2] zp_packed: 262,144 int32, each holding 2 uint4 zero points (low first)
// d_out   out:      67,108,864 fp32 = (w - zp) * scale, rounded through fp16
//
// Structure = R8 winner (70.0us): grid-stride, per iter one dense nontemporal
// int2 load (8B/lane) -> dense cached float4 store (16B/lane); zp+scale on
// the SCALAR path (wave-uniform index zi = i>>6).
// Ledger: nt stores -21% (R4); 16B/lane loads -13% (R5); strided batch-4 -8%
// (R6); nt loads +9% (R7); scalar side-loads +9% (R8).
// Single change vs R8: SOFTWARE PIPELINE DEPTH 2 — issue iteration k+1's
// x-load (and scalar zp/scale loads) before computing/storing iteration k.
// Little's law says the read stream is ~2x under-covered on HBM latency
// (one 512B wave-load in flight per wave). Unlike R6 (grouped 4+4, 16MB
// window), this keeps one stream, 8MB window, loads overlapped with stores.

typedef int i32x2 __attribute__((ext_vector_type(2)));

__global__ void __launch_bounds__(256)
int4_dequant_kernel(const int* __restrict__ x,
                    const float* __restrict__ scale,
                    const int* __restrict__ zp,
                    float* __restrict__ out,
                    int niter)
{
    const int S     = gridDim.x * blockDim.x;         // 524,288 (mult of 64)
    const int tid   = blockIdx.x * blockDim.x + threadIdx.x;
    const int hi    = (threadIdx.x >> 5) & 1;         // lane<32 -> 0, else 1
    const int zstep = S >> 6;                         // 8,192 (uniform)
    int zi = __builtin_amdgcn_readfirstlane(tid >> 6);

    const i32x2*  x2  = reinterpret_cast<const i32x2*>(x);
    const float2* sc2 = reinterpret_cast<const float2*>(scale);
    float4*       o4  = reinterpret_cast<float4*>(out);

    if (tid >= niter) return;

    // prologue: first chunk's loads in flight
    i32x2  w   = __builtin_nontemporal_load(x2 + tid);
    int    zpw = zp[zi];
    float2 sc  = sc2[zi];

    for (int i = tid; i < niter; ) {
        int in = i + S;
        int zn = zi + zstep;

        // issue NEXT chunk's loads before touching current data
        i32x2  wn;
        int    zpwn = 0;
        float2 scn;
        bool more = in < niter;
        if (more) {
            wn   = __builtin_nontemporal_load(x2 + in);
            zpwn = zp[zn];
            scn  = sc2[zn];
        }

        // compute + store current chunk
        float s  = hi ? sc.y : sc.x;
        float zf = (float)((zpw >> (hi << 2)) & 15);
        // fp32 product of an fp16-representable scale and a <=5-bit int is
        // exact; one rounding to fp16 reproduces the reference's fp16 multiply.
        float4 o;
        o.x = (float)(_Float16)(((float)( w.x       & 15) - zf) * s);
        o.y = (float)(_Float16)(((float)((w.x >> 4) & 15) - zf) * s);
        o.z = (float)(_Float16)(((float)( w.y       & 15) - zf) * s);
        o.w = (float)(_Float16)(((float)((w.y >> 4) & 15) - zf) * s);
        o4[i] = o;

        if (!more) break;
        w = wn; zpw = zpwn; sc = scn;
        i = in; zi = zn;
    }
}

extern "C" void kernel_launch(void* const* d_in, const int* in_sizes, int n_in,
                              void* d_out, int out_size, void* d_ws, size_t ws_size,
                              hipStream_t stream) {
    const int*   x     = (const int*)d_in[0];
    const float* scale = (const float*)d_in[1];
    const int*   zp    = (const int*)d_in[2];
    float*       out   = (float*)d_out;

    const int niter = out_size / 4;   // 4 outputs per iteration = 16,777,216

    dim3 grid(2048), block(256);      // 8 blocks/CU, 32 waves/CU, grid-stride x32
    hipLaunchKernelGGL(int4_dequant_kernel, grid, block, 0, stream,
                       x, scale, zp, out, niter);
}